// Round 3
// baseline (585.922 us; speedup 1.0000x reference)
//
#include <hip/hip_runtime.h>

#define BB 4
#define CC 96
#define HH 64
#define WW 64
#define LL 4096
#define KK 3
#define RR 6
#define NN 16

__device__ __forceinline__ float geluf(float x){
    return 0.5f * x * (1.0f + erff(x * 0.70710678118654752f));
}
__device__ __forceinline__ float softplusf(float x){
    return fmaxf(x, 0.0f) + log1pf(expf(-fabsf(x)));
}
__device__ __forceinline__ float sigmoidf(float x){
    return 1.0f / (1.0f + expf(-x));
}

// ---------------- Kernel A: per-(b,c) spatial mean ----------------
__global__ __launch_bounds__(256) void k_mean(const float* __restrict__ x, float* __restrict__ xc){
    int bc = blockIdx.x; // 0..B*C-1
    const float* p = x + (size_t)bc * LL;
    float s = 0.f;
    for (int i = threadIdx.x; i < LL; i += 256) s += p[i];
    __shared__ float red[256];
    red[threadIdx.x] = s; __syncthreads();
    for (int st = 128; st > 0; st >>= 1){
        if (threadIdx.x < st) red[threadIdx.x] += red[threadIdx.x + st];
        __syncthreads();
    }
    if (threadIdx.x == 0) xc[bc] = red[0] * (1.0f / LL);
}

// ---------------- Kernel B: channel-attention MLP ----------------
__global__ __launch_bounds__(128) void k_ca(const float* __restrict__ xc,
                     const float* __restrict__ w1, const float* __restrict__ b1,
                     const float* __restrict__ w2, const float* __restrict__ b2,
                     float* __restrict__ ca){
    int b = blockIdx.x;
    int t = threadIdx.x;
    __shared__ float hid[CC/16];
    if (t < CC/16){
        float a = b1[t];
        for (int d = 0; d < CC; d++) a += w1[t*CC + d] * xc[b*CC + d];
        hid[t] = geluf(a);
    }
    __syncthreads();
    if (t < CC){
        float a = b2[t];
        #pragma unroll
        for (int i = 0; i < CC/16; i++) a += w2[t*(CC/16) + i] * hid[i];
        ca[b*CC + t] = sigmoidf(a);
    }
}

// ---------------- Kernel C: depthwise 9x9 conv + bias, scaled by ca ----------------
__global__ __launch_bounds__(256) void k_conv(const float* __restrict__ x, const float* __restrict__ w,
                       const float* __restrict__ bias, const float* __restrict__ ca,
                       float* __restrict__ x1){
    int gid = blockIdx.x * 256 + threadIdx.x; // B*C*L
    int l = gid & (LL-1); int bc = gid >> 12;
    int c = bc % CC; int b = bc / CC;
    int h = l >> 6, wq = l & 63;
    const float* xp = x + (size_t)bc * LL;
    const float* wp = w + c * 81;
    float acc = 0.f;
    #pragma unroll
    for (int ky = 0; ky < 9; ky++){
        int yy = h + ky - 4;
        if (yy < 0 || yy >= HH) continue;
        #pragma unroll
        for (int kx = 0; kx < 9; kx++){
            int xx = wq + kx - 4;
            if (xx < 0 || xx >= WW) continue;
            acc += xp[yy*WW + xx] * wp[ky*9 + kx];
        }
    }
    x1[gid] = (acc + bias[c]) * ca[b*CC + c];
}

// ---------------- Kernel D: rpe resize 7x7 -> 64x64 (b-independent) ----------------
__global__ __launch_bounds__(256) void k_rpe(const float* __restrict__ t, float* __restrict__ out){
    int gid = blockIdx.x * 256 + threadIdx.x; // C*L
    int l = gid & (LL-1); int c = gid >> 12;
    int h = l >> 6, w = l & 63;
    float sy = fmaxf((h + 0.5f) * (7.0f/64.0f) - 0.5f, 0.f);
    float sx = fmaxf((w + 0.5f) * (7.0f/64.0f) - 0.5f, 0.f);
    int y0 = (int)floorf(sy); int x0 = (int)floorf(sx);
    float wy = sy - (float)y0, wx = sx - (float)x0;
    int y1 = min(y0 + 1, 6), x1i = min(x0 + 1, 6);
    const float* tp = t + c * 49;
    float r0 = tp[y0*7 + x0] * (1.f - wy) + tp[y1*7 + x0] * wy;
    float r1 = tp[y0*7 + x1i] * (1.f - wy) + tp[y1*7 + x1i] * wy;
    out[gid] = r0 * (1.f - wx) + r1 * wx;
}

// ---------------- Kernel E: LayerNorm(C) + GELU + 1x1 conv -> pos/path ----------------
__global__ __launch_bounds__(256) void k_off(const float* __restrict__ x1,
                      const float* __restrict__ g, const float* __restrict__ bta,
                      const float* __restrict__ w2,
                      float* __restrict__ posy, float* __restrict__ posx, float* __restrict__ path){
    int gid = blockIdx.x * 256 + threadIdx.x; // B*L
    int l = gid & (LL-1); int b = gid >> 12;
    const float* p = x1 + (size_t)b * CC * LL + l;
    float s = 0.f, ss = 0.f;
    for (int c = 0; c < CC; c++){
        float v = p[(size_t)c * LL];
        s += v; ss += v * v;
    }
    float m = s * (1.0f / CC);
    float var = ss * (1.0f / CC) - m * m;
    float rstd = rsqrtf(var + 1e-5f);
    float a0 = 0.f, a1 = 0.f, a2 = 0.f;
    for (int c = 0; c < CC; c++){
        float v = p[(size_t)c * LL];
        float xn = (v - m) * rstd * g[c] + bta[c];
        float xg = geluf(xn);
        a0 += w2[c] * xg;
        a1 += w2[CC + c] * xg;
        a2 += w2[2*CC + c] * xg;
    }
    int h = l >> 6, w = l & 63;
    float ry = (2*h + 1) * (1.0f/63.0f) - 1.0f;
    float rx = (2*w + 1) * (1.0f/63.0f) - 1.0f;
    posy[gid] = tanhf(a0) * (1.0f/63.0f) + ry;
    posx[gid] = tanhf(a1) * (1.0f/63.0f) + rx;
    path[gid] = tanhf(a2) + ((l + 0.5f) * (2.0f/4095.0f) - 1.0f);
}

// ---------------- Kernel F: stable bitonic argsort of path_pos (per batch) ----------------
__global__ __launch_bounds__(1024) void k_sort(const float* __restrict__ path,
                                               int* __restrict__ idx, int* __restrict__ inv){
    int b = blockIdx.x;
    __shared__ float key[LL];
    __shared__ int   id[LL];
    for (int i = threadIdx.x; i < LL; i += 1024){ key[i] = path[b*LL + i]; id[i] = i; }
    __syncthreads();
    for (int kk = 2; kk <= LL; kk <<= 1){
        for (int j = kk >> 1; j > 0; j >>= 1){
            for (int i = threadIdx.x; i < LL; i += 1024){
                int ixj = i ^ j;
                if (ixj > i){
                    bool up = ((i & kk) == 0);
                    float ka = key[i], kb = key[ixj];
                    int ia = id[i], ib = id[ixj];
                    bool sw = up ? (kb < ka || (kb == ka && ib < ia))
                                 : (ka < kb || (ka == kb && ia < ib));
                    if (sw){ key[i] = kb; key[ixj] = ka; id[i] = ib; id[ixj] = ia; }
                }
            }
            __syncthreads();
        }
    }
    for (int i = threadIdx.x; i < LL; i += 1024){
        idx[b*LL + i] = id[i];
        inv[b*LL + id[i]] = i;
    }
}

// ---------------- bilinear sample, zero padding ----------------
__device__ __forceinline__ float bilin0(const float* __restrict__ img, float gx, float gy){
    float fx = (gx + 1.f) * 31.5f;   // (W-1)/2 = 31.5
    float fy = (gy + 1.f) * 31.5f;
    float x0f = floorf(fx), y0f = floorf(fy);
    float wx = fx - x0f, wy = fy - y0f;
    int x0 = (int)x0f, y0 = (int)y0f;
    float acc = 0.f;
    bool vx0 = (x0 >= 0) & (x0 < WW), vx1 = (x0+1 >= 0) & (x0+1 < WW);
    bool vy0 = (y0 >= 0) & (y0 < HH), vy1 = (y0+1 >= 0) & (y0+1 < HH);
    if (vy0 & vx0) acc += img[y0*WW + x0]       * (1.f-wx) * (1.f-wy);
    if (vy0 & vx1) acc += img[y0*WW + x0+1]     * wx       * (1.f-wy);
    if (vy1 & vx0) acc += img[(y0+1)*WW + x0]   * (1.f-wx) * wy;
    if (vy1 & vx1) acc += img[(y0+1)*WW + x0+1] * wx       * wy;
    return acc;
}

// ---------------- Kernel S: x grid-sample + rpe grid-sample -> xd ----------------
__global__ __launch_bounds__(256) void k_sample(const float* __restrict__ x, const float* __restrict__ rpe,
                         const float* __restrict__ posy, const float* __restrict__ posx,
                         float* __restrict__ xd){
    int gid = blockIdx.x * 256 + threadIdx.x; // B*C*L
    int l = gid & (LL-1); int bc = gid >> 12;
    int b = bc / CC; int c = bc % CC;
    float gy = posy[b*LL + l], gx = posx[b*LL + l];
    float v = bilin0(x + (size_t)bc * LL, gx, gy);
    int h = l >> 6, w = l & 63;
    float ky = h * (128.0f/3969.0f) - 1.0f;  // linspace(0,64,64)/63*2-1
    float kx = w * (128.0f/3969.0f) - 1.0f;
    float v2 = bilin0(rpe + (size_t)c * LL, (kx - gx) * 0.5f, (ky - gy) * 0.5f);
    xd[gid] = v + v2;
}

// ---------------- Kernel G: build xs & project: x_dbl, dt(softplus), B, C ----------------
__global__ __launch_bounds__(256) void k_proj(const float* __restrict__ x, const float* __restrict__ xd,
    const int* __restrict__ indices, const float* __restrict__ xpw, const float* __restrict__ dtw,
    const float* __restrict__ dtb, float* __restrict__ u2, float* __restrict__ dt,
    float* __restrict__ Bst, float* __restrict__ Cst){
    int blk = blockIdx.x;          // B*K*16 blocks
    int ltile = blk & 15; int bk = blk >> 4;
    int k = bk % KK; int b = bk / KK;
    __shared__ float Wk[38*CC];
    __shared__ float Dw[CC*RR];
    __shared__ float Db[CC];
    for (int i = threadIdx.x; i < 38*CC; i += 256) Wk[i] = xpw[k*38*CC + i];
    for (int i = threadIdx.x; i < CC*RR; i += 256) Dw[i] = dtw[k*CC*RR + i];
    for (int i = threadIdx.x; i < CC;    i += 256) Db[i] = dtb[k*CC + i];
    __syncthreads();
    int l = ltile * 256 + threadIdx.x;
    float acc[38];
    #pragma unroll
    for (int i = 0; i < 38; i++) acc[i] = 0.f;
    int srcl = (k == 0) ? l : (k == 1 ? (LL-1-l) : indices[b*LL + l]);
    const float* xp = (k == 2 ? xd : x) + (size_t)b * CC * LL;
    for (int d = 0; d < CC; d++){
        float v = xp[(size_t)d * LL + srcl];
        if (k == 2) u2[((size_t)b*CC + d) * LL + l] = v;
        #pragma unroll
        for (int i = 0; i < 38; i++) acc[i] += Wk[i*CC + d] * v;
    }
    size_t base = ((size_t)bk * LL + l) * NN;
    #pragma unroll
    for (int n = 0; n < NN; n++){
        Bst[base + n] = acc[RR + n];
        Cst[base + n] = acc[RR + NN + n];
    }
    for (int d = 0; d < CC; d++){
        float sdt = Db[d];
        #pragma unroll
        for (int r = 0; r < RR; r++) sdt += acc[r] * Dw[d*RR + r];
        dt[((size_t)bk * CC + d) * LL + l] = softplusf(sdt);
    }
}

// ---------------- Kernel H: chunked-parallel selective scan (templated source/direction) ----------------
// KIND 0: u = x forward; KIND 1: u = x reversed; KIND 2: u = u2 forward.
// Block = one (b,d) for the given k. 512 threads = 16 n-lanes x 32 segments of T=128.
#define ST 32          // segments
#define TT 128         // steps per segment
template<int KIND>
__global__ __launch_bounds__(512) void k_scan(const float* __restrict__ usrc,
    const float* __restrict__ dt, const float* __restrict__ Bst, const float* __restrict__ Cst,
    const float* __restrict__ Alog, const float* __restrict__ Ds, float* __restrict__ ys){
    constexpr int k = KIND;
    int blk = blockIdx.x;              // b*CC + d
    int d = blk % CC; int b = blk / CC;
    int bk = b * KK + k;
    int tid = threadIdx.x;
    int n = tid & 15; int s = tid >> 4;      // s in [0,32)
    int t0 = s * TT;

    float A  = -__expf(Alog[(k*CC + d)*NN + n]);
    float Dv = Ds[k*CC + d];

    const float* dtp = dt + ((size_t)bk * CC + d) * LL + t0;
    const float* up = (KIND == 1)
        ? usrc + ((size_t)b*CC + d) * LL + (LL-1-t0)
        : usrc + ((size_t)b*CC + d) * LL + t0;
    const float* Bp = Bst + ((size_t)bk * LL + t0) * NN + n;
    const float* Cp = Cst + ((size_t)bk * LL + t0) * NN + n;
    float* yp = ys + ((size_t)bk * CC + d) * LL + t0;

    // Phase 1: local segment scan from h=0, track product of a
    float Aprod = 1.f, h = 0.f;
    #pragma unroll 8
    for (int t = 0; t < TT; t++){
        float dtv = dtp[t];
        float uv  = (KIND == 1) ? up[-t] : up[t];
        float Bv  = Bp[t * NN];
        float a = __expf(dtv * A);
        Aprod *= a;
        h = fmaf(a, h, dtv * uv * Bv);
    }

    // Phase 2: exclusive scan of (Aprod, h) over segments, per chain n
    __shared__ float sA[ST*16];
    __shared__ float sB[ST*16];
    __shared__ float sCin[ST*16];
    sA[s*16 + n] = Aprod;
    sB[s*16 + n] = h;
    __syncthreads();
    if (tid < 16){
        float c = 0.f;
        #pragma unroll
        for (int ss = 0; ss < ST; ss++){
            sCin[ss*16 + tid] = c;
            c = fmaf(sA[ss*16 + tid], c, sB[ss*16 + tid]);
        }
    }
    __syncthreads();
    float hc = sCin[s*16 + n];

    // Phase 3: replay with carry-in, emit y
    #pragma unroll 4
    for (int t = 0; t < TT; t++){
        float dtv = dtp[t];
        float uv  = (KIND == 1) ? up[-t] : up[t];
        float Bv  = Bp[t * NN];
        float Cv  = Cp[t * NN];
        float a = __expf(dtv * A);
        hc = fmaf(a, hc, dtv * uv * Bv);
        float p = hc * Cv;
        p += __shfl_xor(p, 1);
        p += __shfl_xor(p, 2);
        p += __shfl_xor(p, 4);
        p += __shfl_xor(p, 8);
        if (n == 0) yp[t] = fmaf(uv, Dv, p);
    }
}

// ---------------- Kernel I: combine 3 paths + transpose to (B,L,C) ----------------
__global__ __launch_bounds__(256) void k_comb(const float* __restrict__ ys, const int* __restrict__ inv,
                                              float* __restrict__ out){
    int tile = blockIdx.x & 63; int b = blockIdx.x >> 6;
    int l0 = tile * 64;
    __shared__ float t0[CC * 65];
    __shared__ int invs[64];
    if (threadIdx.x < 64) invs[threadIdx.x] = inv[b*LL + l0 + threadIdx.x];
    __syncthreads();
    const float* y0p = ys + (size_t)(b*KK + 0) * CC * LL;
    const float* y1p = ys + (size_t)(b*KK + 1) * CC * LL;
    const float* y2p = ys + (size_t)(b*KK + 2) * CC * LL;
    for (int it = 0; it < 24; it++){
        int e = it * 256 + threadIdx.x;
        int li = e & 63; int c = e >> 6;
        int l = l0 + li;
        float v = y0p[(size_t)c*LL + l] + y1p[(size_t)c*LL + (LL-1-l)] + y2p[(size_t)c*LL + invs[li]];
        t0[c*65 + li] = v * (1.0f/3.0f);
    }
    __syncthreads();
    for (int it = 0; it < 24; it++){
        int e = it * 256 + threadIdx.x;
        int c = e % CC; int li = e / CC;
        out[((size_t)b*LL + l0 + li) * CC + c] = t0[c*65 + li];
    }
}

extern "C" void kernel_launch(void* const* d_in, const int* in_sizes, int n_in,
                              void* d_out, int out_size, void* d_ws, size_t ws_size,
                              hipStream_t stream){
    const float* x    = (const float*)d_in[0];
    const float* xpw  = (const float*)d_in[1];
    const float* dtw  = (const float*)d_in[2];
    const float* dtb  = (const float*)d_in[3];
    const float* Alog = (const float*)d_in[4];
    const float* Ds   = (const float*)d_in[5];
    const float* c1w  = (const float*)d_in[6];
    const float* c1b  = (const float*)d_in[7];
    const float* ca1w = (const float*)d_in[8];
    const float* ca1b = (const float*)d_in[9];
    const float* ca2w = (const float*)d_in[10];
    const float* ca2b = (const float*)d_in[11];
    const float* lng  = (const float*)d_in[12];
    const float* lnb  = (const float*)d_in[13];
    const float* c2w  = (const float*)d_in[14];
    const float* rpet = (const float*)d_in[15];
    float* out = (float*)d_out;

    float* ws   = (float*)d_ws;
    float* xc   = ws;                      // 384
    float* ca   = xc + 384;                // 384
    float* x1   = ca + 384;                // B*C*L = 1572864
    float* rpe  = x1 + (size_t)BB*CC*LL;   // C*L = 393216
    float* posy = rpe + (size_t)CC*LL;     // B*L
    float* posx = posy + (size_t)BB*LL;
    float* path = posx + (size_t)BB*LL;
    float* xd   = path + (size_t)BB*LL;    // B*C*L
    int*   idx  = (int*)(xd + (size_t)BB*CC*LL);   // B*L ints
    int*   inv  = idx + (size_t)BB*LL;             // B*L ints
    float* u2   = (float*)(inv + (size_t)BB*LL);   // B*C*L
    float* dtA  = u2 + (size_t)BB*CC*LL;           // B*K*C*L = 4718592
    float* Bst  = dtA + (size_t)BB*KK*CC*LL;       // B*K*L*N = 786432
    float* Cst  = Bst + (size_t)BB*KK*LL*NN;
    float* ysA  = Cst + (size_t)BB*KK*LL*NN;       // B*K*C*L

    k_mean  <<<BB*CC, 256, 0, stream>>>(x, xc);
    k_ca    <<<BB, 128, 0, stream>>>(xc, ca1w, ca1b, ca2w, ca2b, ca);
    k_conv  <<<(BB*CC*LL)/256, 256, 0, stream>>>(x, c1w, c1b, ca, x1);
    k_rpe   <<<(CC*LL)/256, 256, 0, stream>>>(rpet, rpe);
    k_off   <<<(BB*LL)/256, 256, 0, stream>>>(x1, lng, lnb, c2w, posy, posx, path);
    k_sort  <<<BB, 1024, 0, stream>>>(path, idx, inv);
    k_sample<<<(BB*CC*LL)/256, 256, 0, stream>>>(x, rpe, posy, posx, xd);
    k_proj  <<<BB*KK*16, 256, 0, stream>>>(x, xd, idx, xpw, dtw, dtb, u2, dtA, Bst, Cst);
    k_scan<0><<<BB*CC, 512, 0, stream>>>(x,  dtA, Bst, Cst, Alog, Ds, ysA);
    k_scan<1><<<BB*CC, 512, 0, stream>>>(x,  dtA, Bst, Cst, Alog, Ds, ysA);
    k_scan<2><<<BB*CC, 512, 0, stream>>>(u2, dtA, Bst, Cst, Alog, Ds, ysA);
    k_comb  <<<BB*64, 256, 0, stream>>>(ysA, inv, out);
}

// Round 4
// 509.627 us; speedup vs baseline: 1.1497x; 1.1497x over previous
//
#include <hip/hip_runtime.h>

#define BB 4
#define CC 96
#define HH 64
#define WW 64
#define LL 4096
#define KK 3
#define RR 6
#define NN 16

__device__ __forceinline__ float geluf(float x){
    return 0.5f * x * (1.0f + erff(x * 0.70710678118654752f));
}
__device__ __forceinline__ float softplusf(float x){
    return fmaxf(x, 0.0f) + log1pf(expf(-fabsf(x)));
}
__device__ __forceinline__ float sigmoidf(float x){
    return 1.0f / (1.0f + expf(-x));
}

// ---------------- Kernel A: per-(b,c) spatial mean ----------------
__global__ __launch_bounds__(256) void k_mean(const float* __restrict__ x, float* __restrict__ xc){
    int bc = blockIdx.x; // 0..B*C-1
    const float* p = x + (size_t)bc * LL;
    float s = 0.f;
    for (int i = threadIdx.x; i < LL; i += 256) s += p[i];
    __shared__ float red[256];
    red[threadIdx.x] = s; __syncthreads();
    for (int st = 128; st > 0; st >>= 1){
        if (threadIdx.x < st) red[threadIdx.x] += red[threadIdx.x + st];
        __syncthreads();
    }
    if (threadIdx.x == 0) xc[bc] = red[0] * (1.0f / LL);
}

// ---------------- Kernel B: channel-attention MLP ----------------
__global__ __launch_bounds__(128) void k_ca(const float* __restrict__ xc,
                     const float* __restrict__ w1, const float* __restrict__ b1,
                     const float* __restrict__ w2, const float* __restrict__ b2,
                     float* __restrict__ ca){
    int b = blockIdx.x;
    int t = threadIdx.x;
    __shared__ float hid[CC/16];
    if (t < CC/16){
        float a = b1[t];
        for (int d = 0; d < CC; d++) a += w1[t*CC + d] * xc[b*CC + d];
        hid[t] = geluf(a);
    }
    __syncthreads();
    if (t < CC){
        float a = b2[t];
        #pragma unroll
        for (int i = 0; i < CC/16; i++) a += w2[t*(CC/16) + i] * hid[i];
        ca[b*CC + t] = sigmoidf(a);
    }
}

// ---------------- Kernel C: depthwise 9x9 conv + bias, scaled by ca ----------------
__global__ __launch_bounds__(256) void k_conv(const float* __restrict__ x, const float* __restrict__ w,
                       const float* __restrict__ bias, const float* __restrict__ ca,
                       float* __restrict__ x1){
    int gid = blockIdx.x * 256 + threadIdx.x; // B*C*L
    int l = gid & (LL-1); int bc = gid >> 12;
    int c = bc % CC; int b = bc / CC;
    int h = l >> 6, wq = l & 63;
    const float* xp = x + (size_t)bc * LL;
    const float* wp = w + c * 81;
    float acc = 0.f;
    #pragma unroll
    for (int ky = 0; ky < 9; ky++){
        int yy = h + ky - 4;
        if (yy < 0 || yy >= HH) continue;
        #pragma unroll
        for (int kx = 0; kx < 9; kx++){
            int xx = wq + kx - 4;
            if (xx < 0 || xx >= WW) continue;
            acc += xp[yy*WW + xx] * wp[ky*9 + kx];
        }
    }
    x1[gid] = (acc + bias[c]) * ca[b*CC + c];
}

// ---------------- Kernel D: rpe resize 7x7 -> 64x64 (b-independent) ----------------
__global__ __launch_bounds__(256) void k_rpe(const float* __restrict__ t, float* __restrict__ out){
    int gid = blockIdx.x * 256 + threadIdx.x; // C*L
    int l = gid & (LL-1); int c = gid >> 12;
    int h = l >> 6, w = l & 63;
    float sy = fmaxf((h + 0.5f) * (7.0f/64.0f) - 0.5f, 0.f);
    float sx = fmaxf((w + 0.5f) * (7.0f/64.0f) - 0.5f, 0.f);
    int y0 = (int)floorf(sy); int x0 = (int)floorf(sx);
    float wy = sy - (float)y0, wx = sx - (float)x0;
    int y1 = min(y0 + 1, 6), x1i = min(x0 + 1, 6);
    const float* tp = t + c * 49;
    float r0 = tp[y0*7 + x0] * (1.f - wy) + tp[y1*7 + x0] * wy;
    float r1 = tp[y0*7 + x1i] * (1.f - wy) + tp[y1*7 + x1i] * wy;
    out[gid] = r0 * (1.f - wx) + r1 * wx;
}

// ---------------- Kernel E: LayerNorm(C) + GELU + 1x1 conv -> pos/path ----------------
__global__ __launch_bounds__(256) void k_off(const float* __restrict__ x1,
                      const float* __restrict__ g, const float* __restrict__ bta,
                      const float* __restrict__ w2,
                      float* __restrict__ posy, float* __restrict__ posx, float* __restrict__ path){
    int gid = blockIdx.x * 256 + threadIdx.x; // B*L
    int l = gid & (LL-1); int b = gid >> 12;
    const float* p = x1 + (size_t)b * CC * LL + l;
    float s = 0.f, ss = 0.f;
    for (int c = 0; c < CC; c++){
        float v = p[(size_t)c * LL];
        s += v; ss += v * v;
    }
    float m = s * (1.0f / CC);
    float var = ss * (1.0f / CC) - m * m;
    float rstd = rsqrtf(var + 1e-5f);
    float a0 = 0.f, a1 = 0.f, a2 = 0.f;
    for (int c = 0; c < CC; c++){
        float v = p[(size_t)c * LL];
        float xn = (v - m) * rstd * g[c] + bta[c];
        float xg = geluf(xn);
        a0 += w2[c] * xg;
        a1 += w2[CC + c] * xg;
        a2 += w2[2*CC + c] * xg;
    }
    int h = l >> 6, w = l & 63;
    float ry = (2*h + 1) * (1.0f/63.0f) - 1.0f;
    float rx = (2*w + 1) * (1.0f/63.0f) - 1.0f;
    posy[gid] = tanhf(a0) * (1.0f/63.0f) + ry;
    posx[gid] = tanhf(a1) * (1.0f/63.0f) + rx;
    path[gid] = tanhf(a2) + ((l + 0.5f) * (2.0f/4095.0f) - 1.0f);
}

// ---------------- Kernel F: hybrid register/shuffle/LDS stable bitonic argsort ----------------
// Thread t owns elements e = 4t..4t+3 packed as (sortable_key<<32)|index (u64).
// Stride j exchanges: j in {1,2} in-register, j in [4,128] via wave shuffle (partner
// thread t^(j/4) same wave64), j >= 256 via LDS (2 barriers/round, 10 rounds total).
typedef unsigned long long u64s;
__device__ __forceinline__ u64s shflx64(u64s x, int m){
    int lo = __shfl_xor((int)(unsigned)x, m);
    int hi = __shfl_xor((int)(unsigned)(x >> 32), m);
    return ((u64s)(unsigned)hi << 32) | (unsigned)lo;
}
__device__ __forceinline__ void cex(u64s& a, u64s& b, bool up){
    u64s mn = a < b ? a : b;
    u64s mx = a < b ? b : a;
    a = up ? mn : mx;
    b = up ? mx : mn;
}
__global__ __launch_bounds__(1024) void k_sort(const float* __restrict__ path,
                                               int* __restrict__ idx, int* __restrict__ inv){
    int b = blockIdx.x;
    int t = threadIdx.x;
    __shared__ u64s lds[LL];
    u64s v[4];
    #pragma unroll
    for (int r = 0; r < 4; r++){
        int e = t*4 + r;
        unsigned u = __float_as_uint(path[b*LL + e]);
        u ^= (u >> 31) ? 0xFFFFFFFFu : 0x80000000u;   // monotonic float->uint
        v[r] = ((u64s)u << 32) | (unsigned)e;
    }
    for (int kk = 2; kk <= LL; kk <<= 1){
        for (int j = kk >> 1; j > 0; j >>= 1){
            if (j >= 256){
                __syncthreads();
                #pragma unroll
                for (int r = 0; r < 4; r++) lds[t*4 + r] = v[r];
                __syncthreads();
                #pragma unroll
                for (int r = 0; r < 4; r++){
                    int e = t*4 + r;
                    u64s pv = lds[e ^ j];
                    bool up    = ((e & kk) == 0);
                    bool lower = ((e & j) == 0);
                    u64s mn = v[r] < pv ? v[r] : pv;
                    u64s mx = v[r] < pv ? pv : v[r];
                    v[r] = (up == lower) ? mn : mx;
                }
            } else if (j >= 4){
                int m = j >> 2;
                #pragma unroll
                for (int r = 0; r < 4; r++){
                    u64s pv = shflx64(v[r], m);
                    bool up    = (((t*4 + r) & kk) == 0);
                    bool lower = ((t & m) == 0);
                    u64s mn = v[r] < pv ? v[r] : pv;
                    u64s mx = v[r] < pv ? pv : v[r];
                    v[r] = (up == lower) ? mn : mx;
                }
            } else if (j == 2){
                bool up = (((t*4) & kk) == 0);   // kk>=4 here: uniform over quad
                cex(v[0], v[2], up);
                cex(v[1], v[3], up);
            } else { // j == 1
                if (kk == 2){
                    cex(v[0], v[1], true);    // e=4t+0: (e&2)==0 -> ascending
                    cex(v[2], v[3], false);   // e=4t+2: (e&2)!=0 -> descending
                } else {
                    bool up = (((t*4) & kk) == 0);
                    cex(v[0], v[1], up);
                    cex(v[2], v[3], up);
                }
            }
        }
    }
    #pragma unroll
    for (int r = 0; r < 4; r++){
        int e = t*4 + r;
        int id = (int)(unsigned)(v[r] & 0xFFFFFFFFu);
        idx[b*LL + e] = id;
        inv[b*LL + id] = e;
    }
}

// ---------------- bilinear sample, zero padding ----------------
__device__ __forceinline__ float bilin0(const float* __restrict__ img, float gx, float gy){
    float fx = (gx + 1.f) * 31.5f;   // (W-1)/2 = 31.5
    float fy = (gy + 1.f) * 31.5f;
    float x0f = floorf(fx), y0f = floorf(fy);
    float wx = fx - x0f, wy = fy - y0f;
    int x0 = (int)x0f, y0 = (int)y0f;
    float acc = 0.f;
    bool vx0 = (x0 >= 0) & (x0 < WW), vx1 = (x0+1 >= 0) & (x0+1 < WW);
    bool vy0 = (y0 >= 0) & (y0 < HH), vy1 = (y0+1 >= 0) & (y0+1 < HH);
    if (vy0 & vx0) acc += img[y0*WW + x0]       * (1.f-wx) * (1.f-wy);
    if (vy0 & vx1) acc += img[y0*WW + x0+1]     * wx       * (1.f-wy);
    if (vy1 & vx0) acc += img[(y0+1)*WW + x0]   * (1.f-wx) * wy;
    if (vy1 & vx1) acc += img[(y0+1)*WW + x0+1] * wx       * wy;
    return acc;
}

// ---------------- Kernel S: x grid-sample + rpe grid-sample -> xd ----------------
__global__ __launch_bounds__(256) void k_sample(const float* __restrict__ x, const float* __restrict__ rpe,
                         const float* __restrict__ posy, const float* __restrict__ posx,
                         float* __restrict__ xd){
    int gid = blockIdx.x * 256 + threadIdx.x; // B*C*L
    int l = gid & (LL-1); int bc = gid >> 12;
    int b = bc / CC; int c = bc % CC;
    float gy = posy[b*LL + l], gx = posx[b*LL + l];
    float v = bilin0(x + (size_t)bc * LL, gx, gy);
    int h = l >> 6, w = l & 63;
    float ky = h * (128.0f/3969.0f) - 1.0f;  // linspace(0,64,64)/63*2-1
    float kx = w * (128.0f/3969.0f) - 1.0f;
    float v2 = bilin0(rpe + (size_t)c * LL, (kx - gx) * 0.5f, (ky - gy) * 0.5f);
    xd[gid] = v + v2;
}

// ---------------- Kernel G: build xs & project: x_dbl, dt(softplus), B, C ----------------
__global__ __launch_bounds__(256) void k_proj(const float* __restrict__ x, const float* __restrict__ xd,
    const int* __restrict__ indices, const float* __restrict__ xpw, const float* __restrict__ dtw,
    const float* __restrict__ dtb, float* __restrict__ u2, float* __restrict__ dt,
    float* __restrict__ Bst, float* __restrict__ Cst){
    int blk = blockIdx.x;          // B*K*16 blocks
    int ltile = blk & 15; int bk = blk >> 4;
    int k = bk % KK; int b = bk / KK;
    __shared__ float Wk[38*CC];
    __shared__ float Dw[CC*RR];
    __shared__ float Db[CC];
    for (int i = threadIdx.x; i < 38*CC; i += 256) Wk[i] = xpw[k*38*CC + i];
    for (int i = threadIdx.x; i < CC*RR; i += 256) Dw[i] = dtw[k*CC*RR + i];
    for (int i = threadIdx.x; i < CC;    i += 256) Db[i] = dtb[k*CC + i];
    __syncthreads();
    int l = ltile * 256 + threadIdx.x;
    float acc[38];
    #pragma unroll
    for (int i = 0; i < 38; i++) acc[i] = 0.f;
    int srcl = (k == 0) ? l : (k == 1 ? (LL-1-l) : indices[b*LL + l]);
    const float* xp = (k == 2 ? xd : x) + (size_t)b * CC * LL;
    for (int d = 0; d < CC; d++){
        float v = xp[(size_t)d * LL + srcl];
        if (k == 2) u2[((size_t)b*CC + d) * LL + l] = v;
        #pragma unroll
        for (int i = 0; i < 38; i++) acc[i] += Wk[i*CC + d] * v;
    }
    size_t base = ((size_t)bk * LL + l) * NN;
    #pragma unroll
    for (int n = 0; n < NN; n++){
        Bst[base + n] = acc[RR + n];
        Cst[base + n] = acc[RR + NN + n];
    }
    for (int d = 0; d < CC; d++){
        float sdt = Db[d];
        #pragma unroll
        for (int r = 0; r < RR; r++) sdt += acc[r] * Dw[d*RR + r];
        dt[((size_t)bk * CC + d) * LL + l] = softplusf(sdt);
    }
}

// ---------------- Kernel H: chunked-parallel selective scan (templated source/direction) ----------------
// KIND 0: u = x forward; KIND 1: u = x reversed; KIND 2: u = u2 forward.
// Block = one (b,d) for the given k. 512 threads = 16 n-lanes x 32 segments of T=128.
#define ST 32          // segments
#define TT 128         // steps per segment
template<int KIND>
__global__ __launch_bounds__(512) void k_scan(const float* __restrict__ usrc,
    const float* __restrict__ dt, const float* __restrict__ Bst, const float* __restrict__ Cst,
    const float* __restrict__ Alog, const float* __restrict__ Ds, float* __restrict__ ys){
    constexpr int k = KIND;
    int blk = blockIdx.x;              // b*CC + d
    int d = blk % CC; int b = blk / CC;
    int bk = b * KK + k;
    int tid = threadIdx.x;
    int n = tid & 15; int s = tid >> 4;      // s in [0,32)
    int t0 = s * TT;

    float A  = -__expf(Alog[(k*CC + d)*NN + n]);
    float Dv = Ds[k*CC + d];

    const float* dtp = dt + ((size_t)bk * CC + d) * LL + t0;
    const float* up = (KIND == 1)
        ? usrc + ((size_t)b*CC + d) * LL + (LL-1-t0)
        : usrc + ((size_t)b*CC + d) * LL + t0;
    const float* Bp = Bst + ((size_t)bk * LL + t0) * NN + n;
    const float* Cp = Cst + ((size_t)bk * LL + t0) * NN + n;
    float* yp = ys + ((size_t)bk * CC + d) * LL + t0;

    // Phase 1: local segment scan from h=0, track product of a
    float Aprod = 1.f, h = 0.f;
    #pragma unroll 8
    for (int t = 0; t < TT; t++){
        float dtv = dtp[t];
        float uv  = (KIND == 1) ? up[-t] : up[t];
        float Bv  = Bp[t * NN];
        float a = __expf(dtv * A);
        Aprod *= a;
        h = fmaf(a, h, dtv * uv * Bv);
    }

    // Phase 2: exclusive scan of (Aprod, h) over segments, per chain n
    __shared__ float sA[ST*16];
    __shared__ float sB[ST*16];
    __shared__ float sCin[ST*16];
    sA[s*16 + n] = Aprod;
    sB[s*16 + n] = h;
    __syncthreads();
    if (tid < 16){
        float c = 0.f;
        #pragma unroll
        for (int ss = 0; ss < ST; ss++){
            sCin[ss*16 + tid] = c;
            c = fmaf(sA[ss*16 + tid], c, sB[ss*16 + tid]);
        }
    }
    __syncthreads();
    float hc = sCin[s*16 + n];

    // Phase 3: replay with carry-in, emit y
    #pragma unroll 4
    for (int t = 0; t < TT; t++){
        float dtv = dtp[t];
        float uv  = (KIND == 1) ? up[-t] : up[t];
        float Bv  = Bp[t * NN];
        float Cv  = Cp[t * NN];
        float a = __expf(dtv * A);
        hc = fmaf(a, hc, dtv * uv * Bv);
        float p = hc * Cv;
        p += __shfl_xor(p, 1);
        p += __shfl_xor(p, 2);
        p += __shfl_xor(p, 4);
        p += __shfl_xor(p, 8);
        if (n == 0) yp[t] = fmaf(uv, Dv, p);
    }
}

// ---------------- Kernel I: combine 3 paths + transpose to (B,L,C) ----------------
__global__ __launch_bounds__(256) void k_comb(const float* __restrict__ ys, const int* __restrict__ inv,
                                              float* __restrict__ out){
    int tile = blockIdx.x & 63; int b = blockIdx.x >> 6;
    int l0 = tile * 64;
    __shared__ float t0[CC * 65];
    __shared__ int invs[64];
    if (threadIdx.x < 64) invs[threadIdx.x] = inv[b*LL + l0 + threadIdx.x];
    __syncthreads();
    const float* y0p = ys + (size_t)(b*KK + 0) * CC * LL;
    const float* y1p = ys + (size_t)(b*KK + 1) * CC * LL;
    const float* y2p = ys + (size_t)(b*KK + 2) * CC * LL;
    for (int it = 0; it < 24; it++){
        int e = it * 256 + threadIdx.x;
        int li = e & 63; int c = e >> 6;
        int l = l0 + li;
        float v = y0p[(size_t)c*LL + l] + y1p[(size_t)c*LL + (LL-1-l)] + y2p[(size_t)c*LL + invs[li]];
        t0[c*65 + li] = v * (1.0f/3.0f);
    }
    __syncthreads();
    for (int it = 0; it < 24; it++){
        int e = it * 256 + threadIdx.x;
        int c = e % CC; int li = e / CC;
        out[((size_t)b*LL + l0 + li) * CC + c] = t0[c*65 + li];
    }
}

extern "C" void kernel_launch(void* const* d_in, const int* in_sizes, int n_in,
                              void* d_out, int out_size, void* d_ws, size_t ws_size,
                              hipStream_t stream){
    const float* x    = (const float*)d_in[0];
    const float* xpw  = (const float*)d_in[1];
    const float* dtw  = (const float*)d_in[2];
    const float* dtb  = (const float*)d_in[3];
    const float* Alog = (const float*)d_in[4];
    const float* Ds   = (const float*)d_in[5];
    const float* c1w  = (const float*)d_in[6];
    const float* c1b  = (const float*)d_in[7];
    const float* ca1w = (const float*)d_in[8];
    const float* ca1b = (const float*)d_in[9];
    const float* ca2w = (const float*)d_in[10];
    const float* ca2b = (const float*)d_in[11];
    const float* lng  = (const float*)d_in[12];
    const float* lnb  = (const float*)d_in[13];
    const float* c2w  = (const float*)d_in[14];
    const float* rpet = (const float*)d_in[15];
    float* out = (float*)d_out;

    float* ws   = (float*)d_ws;
    float* xc   = ws;                      // 384
    float* ca   = xc + 384;                // 384
    float* x1   = ca + 384;                // B*C*L = 1572864
    float* rpe  = x1 + (size_t)BB*CC*LL;   // C*L = 393216
    float* posy = rpe + (size_t)CC*LL;     // B*L
    float* posx = posy + (size_t)BB*LL;
    float* path = posx + (size_t)BB*LL;
    float* xd   = path + (size_t)BB*LL;    // B*C*L
    int*   idx  = (int*)(xd + (size_t)BB*CC*LL);   // B*L ints
    int*   inv  = idx + (size_t)BB*LL;             // B*L ints
    float* u2   = (float*)(inv + (size_t)BB*LL);   // B*C*L
    float* dtA  = u2 + (size_t)BB*CC*LL;           // B*K*C*L = 4718592
    float* Bst  = dtA + (size_t)BB*KK*CC*LL;       // B*K*L*N = 786432
    float* Cst  = Bst + (size_t)BB*KK*LL*NN;
    float* ysA  = Cst + (size_t)BB*KK*LL*NN;       // B*K*C*L

    k_mean  <<<BB*CC, 256, 0, stream>>>(x, xc);
    k_ca    <<<BB, 128, 0, stream>>>(xc, ca1w, ca1b, ca2w, ca2b, ca);
    k_conv  <<<(BB*CC*LL)/256, 256, 0, stream>>>(x, c1w, c1b, ca, x1);
    k_rpe   <<<(CC*LL)/256, 256, 0, stream>>>(rpet, rpe);
    k_off   <<<(BB*LL)/256, 256, 0, stream>>>(x1, lng, lnb, c2w, posy, posx, path);
    k_sort  <<<BB, 1024, 0, stream>>>(path, idx, inv);
    k_sample<<<(BB*CC*LL)/256, 256, 0, stream>>>(x, rpe, posy, posx, xd);
    k_proj  <<<BB*KK*16, 256, 0, stream>>>(x, xd, idx, xpw, dtw, dtb, u2, dtA, Bst, Cst);
    k_scan<0><<<BB*CC, 512, 0, stream>>>(x,  dtA, Bst, Cst, Alog, Ds, ysA);
    k_scan<1><<<BB*CC, 512, 0, stream>>>(x,  dtA, Bst, Cst, Alog, Ds, ysA);
    k_scan<2><<<BB*CC, 512, 0, stream>>>(u2, dtA, Bst, Cst, Alog, Ds, ysA);
    k_comb  <<<BB*64, 256, 0, stream>>>(ysA, inv, out);
}

// Round 5
// 505.201 us; speedup vs baseline: 1.1598x; 1.0088x over previous
//
#include <hip/hip_runtime.h>

#define BB 4
#define CC 96
#define HH 64
#define WW 64
#define LL 4096
#define KK 3
#define RR 6
#define NN 16

__device__ __forceinline__ float geluf(float x){
    return 0.5f * x * (1.0f + erff(x * 0.70710678118654752f));
}
__device__ __forceinline__ float softplusf(float x){
    return fmaxf(x, 0.0f) + log1pf(expf(-fabsf(x)));
}
__device__ __forceinline__ float sigmoidf(float x){
    return 1.0f / (1.0f + expf(-x));
}

// ---------------- Kernel A: per-(b,c) spatial mean ----------------
__global__ __launch_bounds__(256) void k_mean(const float* __restrict__ x, float* __restrict__ xc){
    int bc = blockIdx.x; // 0..B*C-1
    const float* p = x + (size_t)bc * LL;
    float s = 0.f;
    for (int i = threadIdx.x; i < LL; i += 256) s += p[i];
    __shared__ float red[256];
    red[threadIdx.x] = s; __syncthreads();
    for (int st = 128; st > 0; st >>= 1){
        if (threadIdx.x < st) red[threadIdx.x] += red[threadIdx.x + st];
        __syncthreads();
    }
    if (threadIdx.x == 0) xc[bc] = red[0] * (1.0f / LL);
}

// ---------------- Kernel B: channel-attention MLP ----------------
__global__ __launch_bounds__(128) void k_ca(const float* __restrict__ xc,
                     const float* __restrict__ w1, const float* __restrict__ b1,
                     const float* __restrict__ w2, const float* __restrict__ b2,
                     float* __restrict__ ca){
    int b = blockIdx.x;
    int t = threadIdx.x;
    __shared__ float hid[CC/16];
    if (t < CC/16){
        float a = b1[t];
        for (int d = 0; d < CC; d++) a += w1[t*CC + d] * xc[b*CC + d];
        hid[t] = geluf(a);
    }
    __syncthreads();
    if (t < CC){
        float a = b2[t];
        #pragma unroll
        for (int i = 0; i < CC/16; i++) a += w2[t*(CC/16) + i] * hid[i];
        ca[b*CC + t] = sigmoidf(a);
    }
}

// ---------------- Kernel C: depthwise 9x9 conv + bias, scaled by ca ----------------
__global__ __launch_bounds__(256) void k_conv(const float* __restrict__ x, const float* __restrict__ w,
                       const float* __restrict__ bias, const float* __restrict__ ca,
                       float* __restrict__ x1){
    int gid = blockIdx.x * 256 + threadIdx.x; // B*C*L
    int l = gid & (LL-1); int bc = gid >> 12;
    int c = bc % CC; int b = bc / CC;
    int h = l >> 6, wq = l & 63;
    const float* xp = x + (size_t)bc * LL;
    const float* wp = w + c * 81;
    float acc = 0.f;
    #pragma unroll
    for (int ky = 0; ky < 9; ky++){
        int yy = h + ky - 4;
        if (yy < 0 || yy >= HH) continue;
        #pragma unroll
        for (int kx = 0; kx < 9; kx++){
            int xx = wq + kx - 4;
            if (xx < 0 || xx >= WW) continue;
            acc += xp[yy*WW + xx] * wp[ky*9 + kx];
        }
    }
    x1[gid] = (acc + bias[c]) * ca[b*CC + c];
}

// ---------------- Kernel D: rpe resize 7x7 -> 64x64 (b-independent) ----------------
__global__ __launch_bounds__(256) void k_rpe(const float* __restrict__ t, float* __restrict__ out){
    int gid = blockIdx.x * 256 + threadIdx.x; // C*L
    int l = gid & (LL-1); int c = gid >> 12;
    int h = l >> 6, w = l & 63;
    float sy = fmaxf((h + 0.5f) * (7.0f/64.0f) - 0.5f, 0.f);
    float sx = fmaxf((w + 0.5f) * (7.0f/64.0f) - 0.5f, 0.f);
    int y0 = (int)floorf(sy); int x0 = (int)floorf(sx);
    float wy = sy - (float)y0, wx = sx - (float)x0;
    int y1 = min(y0 + 1, 6), x1i = min(x0 + 1, 6);
    const float* tp = t + c * 49;
    float r0 = tp[y0*7 + x0] * (1.f - wy) + tp[y1*7 + x0] * wy;
    float r1 = tp[y0*7 + x1i] * (1.f - wy) + tp[y1*7 + x1i] * wy;
    out[gid] = r0 * (1.f - wx) + r1 * wx;
}

// ---------------- Kernel E: LayerNorm(C) + GELU + 1x1 conv -> pos/path ----------------
__global__ __launch_bounds__(256) void k_off(const float* __restrict__ x1,
                      const float* __restrict__ g, const float* __restrict__ bta,
                      const float* __restrict__ w2,
                      float* __restrict__ posy, float* __restrict__ posx, float* __restrict__ path){
    int gid = blockIdx.x * 256 + threadIdx.x; // B*L
    int l = gid & (LL-1); int b = gid >> 12;
    const float* p = x1 + (size_t)b * CC * LL + l;
    float s = 0.f, ss = 0.f;
    for (int c = 0; c < CC; c++){
        float v = p[(size_t)c * LL];
        s += v; ss += v * v;
    }
    float m = s * (1.0f / CC);
    float var = ss * (1.0f / CC) - m * m;
    float rstd = rsqrtf(var + 1e-5f);
    float a0 = 0.f, a1 = 0.f, a2 = 0.f;
    for (int c = 0; c < CC; c++){
        float v = p[(size_t)c * LL];
        float xn = (v - m) * rstd * g[c] + bta[c];
        float xg = geluf(xn);
        a0 += w2[c] * xg;
        a1 += w2[CC + c] * xg;
        a2 += w2[2*CC + c] * xg;
    }
    int h = l >> 6, w = l & 63;
    float ry = (2*h + 1) * (1.0f/63.0f) - 1.0f;
    float rx = (2*w + 1) * (1.0f/63.0f) - 1.0f;
    posy[gid] = tanhf(a0) * (1.0f/63.0f) + ry;
    posx[gid] = tanhf(a1) * (1.0f/63.0f) + rx;
    path[gid] = tanhf(a2) + ((l + 0.5f) * (2.0f/4095.0f) - 1.0f);
}

// ---------------- Kernel F: hybrid register/shuffle/LDS stable bitonic argsort ----------------
typedef unsigned long long u64s;
__device__ __forceinline__ u64s shflx64(u64s x, int m){
    int lo = __shfl_xor((int)(unsigned)x, m);
    int hi = __shfl_xor((int)(unsigned)(x >> 32), m);
    return ((u64s)(unsigned)hi << 32) | (unsigned)lo;
}
__device__ __forceinline__ void cex(u64s& a, u64s& b, bool up){
    u64s mn = a < b ? a : b;
    u64s mx = a < b ? b : a;
    a = up ? mn : mx;
    b = up ? mx : mn;
}
__global__ __launch_bounds__(1024) void k_sort(const float* __restrict__ path,
                                               int* __restrict__ idx, int* __restrict__ inv){
    int b = blockIdx.x;
    int t = threadIdx.x;
    __shared__ u64s lds[LL];
    u64s v[4];
    #pragma unroll
    for (int r = 0; r < 4; r++){
        int e = t*4 + r;
        unsigned u = __float_as_uint(path[b*LL + e]);
        u ^= (u >> 31) ? 0xFFFFFFFFu : 0x80000000u;   // monotonic float->uint
        v[r] = ((u64s)u << 32) | (unsigned)e;
    }
    for (int kk = 2; kk <= LL; kk <<= 1){
        for (int j = kk >> 1; j > 0; j >>= 1){
            if (j >= 256){
                __syncthreads();
                #pragma unroll
                for (int r = 0; r < 4; r++) lds[t*4 + r] = v[r];
                __syncthreads();
                #pragma unroll
                for (int r = 0; r < 4; r++){
                    int e = t*4 + r;
                    u64s pv = lds[e ^ j];
                    bool up    = ((e & kk) == 0);
                    bool lower = ((e & j) == 0);
                    u64s mn = v[r] < pv ? v[r] : pv;
                    u64s mx = v[r] < pv ? pv : v[r];
                    v[r] = (up == lower) ? mn : mx;
                }
            } else if (j >= 4){
                int m = j >> 2;
                #pragma unroll
                for (int r = 0; r < 4; r++){
                    u64s pv = shflx64(v[r], m);
                    bool up    = (((t*4 + r) & kk) == 0);
                    bool lower = ((t & m) == 0);
                    u64s mn = v[r] < pv ? v[r] : pv;
                    u64s mx = v[r] < pv ? pv : v[r];
                    v[r] = (up == lower) ? mn : mx;
                }
            } else if (j == 2){
                bool up = (((t*4) & kk) == 0);
                cex(v[0], v[2], up);
                cex(v[1], v[3], up);
            } else { // j == 1
                if (kk == 2){
                    cex(v[0], v[1], true);
                    cex(v[2], v[3], false);
                } else {
                    bool up = (((t*4) & kk) == 0);
                    cex(v[0], v[1], up);
                    cex(v[2], v[3], up);
                }
            }
        }
    }
    #pragma unroll
    for (int r = 0; r < 4; r++){
        int e = t*4 + r;
        int id = (int)(unsigned)(v[r] & 0xFFFFFFFFu);
        idx[b*LL + e] = id;
        inv[b*LL + id] = e;
    }
}

// ---------------- bilinear sample, zero padding ----------------
__device__ __forceinline__ float bilin0(const float* __restrict__ img, float gx, float gy){
    float fx = (gx + 1.f) * 31.5f;   // (W-1)/2 = 31.5
    float fy = (gy + 1.f) * 31.5f;
    float x0f = floorf(fx), y0f = floorf(fy);
    float wx = fx - x0f, wy = fy - y0f;
    int x0 = (int)x0f, y0 = (int)y0f;
    float acc = 0.f;
    bool vx0 = (x0 >= 0) & (x0 < WW), vx1 = (x0+1 >= 0) & (x0+1 < WW);
    bool vy0 = (y0 >= 0) & (y0 < HH), vy1 = (y0+1 >= 0) & (y0+1 < HH);
    if (vy0 & vx0) acc += img[y0*WW + x0]       * (1.f-wx) * (1.f-wy);
    if (vy0 & vx1) acc += img[y0*WW + x0+1]     * wx       * (1.f-wy);
    if (vy1 & vx0) acc += img[(y0+1)*WW + x0]   * (1.f-wx) * wy;
    if (vy1 & vx1) acc += img[(y0+1)*WW + x0+1] * wx       * wy;
    return acc;
}

// ---------------- Kernel S: x grid-sample + rpe grid-sample -> xd ----------------
__global__ __launch_bounds__(256) void k_sample(const float* __restrict__ x, const float* __restrict__ rpe,
                         const float* __restrict__ posy, const float* __restrict__ posx,
                         float* __restrict__ xd){
    int gid = blockIdx.x * 256 + threadIdx.x; // B*C*L
    int l = gid & (LL-1); int bc = gid >> 12;
    int b = bc / CC; int c = bc % CC;
    float gy = posy[b*LL + l], gx = posx[b*LL + l];
    float v = bilin0(x + (size_t)bc * LL, gx, gy);
    int h = l >> 6, w = l & 63;
    float ky = h * (128.0f/3969.0f) - 1.0f;  // linspace(0,64,64)/63*2-1
    float kx = w * (128.0f/3969.0f) - 1.0f;
    float v2 = bilin0(rpe + (size_t)c * LL, (kx - gx) * 0.5f, (ky - gy) * 0.5f);
    xd[gid] = v + v2;
}

// ---------------- Kernel G: projection with scalar-pipe weights ----------------
// Weights are wave-uniform -> read directly from global (compiler emits s_load,
// constant-cache backed); no LDS staging, no ds_read storm. Block = 1 wave,
// 64 l's; grid = B*K*64 = 768 blocks so every CU is covered (~3 blocks/CU).
__global__ __launch_bounds__(64) void k_proj(const float* __restrict__ x, const float* __restrict__ xd,
    const int* __restrict__ indices, const float* __restrict__ xpw, const float* __restrict__ dtw,
    const float* __restrict__ dtb, float* __restrict__ u2, float* __restrict__ dt,
    float* __restrict__ Bst, float* __restrict__ Cst){
    int blk = blockIdx.x;          // B*K*64 blocks
    int ltile = blk & 63; int bk = blk >> 6;
    int k = bk % KK; int b = bk / KK;
    const float* __restrict__ Wk = xpw + k*38*CC;   // uniform per block
    int l = ltile * 64 + threadIdx.x;
    float acc[38];
    #pragma unroll
    for (int i = 0; i < 38; i++) acc[i] = 0.f;
    int srcl = (k == 0) ? l : (k == 1 ? (LL-1-l) : indices[b*LL + l]);
    const float* xp = (k == 2 ? xd : x) + (size_t)b * CC * LL;
    #pragma unroll 4
    for (int d = 0; d < CC; d++){
        float v = xp[(size_t)d * LL + srcl];
        if (k == 2) u2[((size_t)b*CC + d) * LL + l] = v;
        #pragma unroll
        for (int i = 0; i < 38; i++) acc[i] += Wk[i*CC + d] * v;
    }
    size_t base = ((size_t)bk * LL + l) * NN;
    #pragma unroll
    for (int n = 0; n < NN; n++){
        Bst[base + n] = acc[RR + n];
        Cst[base + n] = acc[RR + NN + n];
    }
    const float* __restrict__ Dw = dtw + k*CC*RR;
    const float* __restrict__ Db = dtb + k*CC;
    #pragma unroll 4
    for (int d = 0; d < CC; d++){
        float sdt = Db[d];
        #pragma unroll
        for (int r = 0; r < RR; r++) sdt += acc[r] * Dw[d*RR + r];
        dt[((size_t)bk * CC + d) * LL + l] = softplusf(sdt);
    }
}

// ---------------- Kernel H: chunked-parallel selective scan (templated source/direction) ----------------
// KIND 0: u = x forward; KIND 1: u = x reversed; KIND 2: u = u2 forward.
#define ST 32          // segments
#define TT 128         // steps per segment
template<int KIND>
__global__ __launch_bounds__(512) void k_scan(const float* __restrict__ usrc,
    const float* __restrict__ dt, const float* __restrict__ Bst, const float* __restrict__ Cst,
    const float* __restrict__ Alog, const float* __restrict__ Ds, float* __restrict__ ys){
    constexpr int k = KIND;
    int blk = blockIdx.x;              // b*CC + d
    int d = blk % CC; int b = blk / CC;
    int bk = b * KK + k;
    int tid = threadIdx.x;
    int n = tid & 15; int s = tid >> 4;      // s in [0,32)
    int t0 = s * TT;

    float A  = -__expf(Alog[(k*CC + d)*NN + n]);
    float Dv = Ds[k*CC + d];

    const float* dtp = dt + ((size_t)bk * CC + d) * LL + t0;
    const float* up = (KIND == 1)
        ? usrc + ((size_t)b*CC + d) * LL + (LL-1-t0)
        : usrc + ((size_t)b*CC + d) * LL + t0;
    const float* Bp = Bst + ((size_t)bk * LL + t0) * NN + n;
    const float* Cp = Cst + ((size_t)bk * LL + t0) * NN + n;
    float* yp = ys + ((size_t)bk * CC + d) * LL + t0;

    // Phase 1: local segment scan from h=0, track product of a
    float Aprod = 1.f, h = 0.f;
    #pragma unroll 8
    for (int t = 0; t < TT; t++){
        float dtv = dtp[t];
        float uv  = (KIND == 1) ? up[-t] : up[t];
        float Bv  = Bp[t * NN];
        float a = __expf(dtv * A);
        Aprod *= a;
        h = fmaf(a, h, dtv * uv * Bv);
    }

    // Phase 2: exclusive scan of (Aprod, h) over segments, per chain n
    __shared__ float sA[ST*16];
    __shared__ float sB[ST*16];
    __shared__ float sCin[ST*16];
    sA[s*16 + n] = Aprod;
    sB[s*16 + n] = h;
    __syncthreads();
    if (tid < 16){
        float c = 0.f;
        #pragma unroll
        for (int ss = 0; ss < ST; ss++){
            sCin[ss*16 + tid] = c;
            c = fmaf(sA[ss*16 + tid], c, sB[ss*16 + tid]);
        }
    }
    __syncthreads();
    float hc = sCin[s*16 + n];

    // Phase 3: replay with carry-in, emit y
    #pragma unroll 4
    for (int t = 0; t < TT; t++){
        float dtv = dtp[t];
        float uv  = (KIND == 1) ? up[-t] : up[t];
        float Bv  = Bp[t * NN];
        float Cv  = Cp[t * NN];
        float a = __expf(dtv * A);
        hc = fmaf(a, hc, dtv * uv * Bv);
        float p = hc * Cv;
        p += __shfl_xor(p, 1);
        p += __shfl_xor(p, 2);
        p += __shfl_xor(p, 4);
        p += __shfl_xor(p, 8);
        if (n == 0) yp[t] = fmaf(uv, Dv, p);
    }
}

// ---------------- Kernel I: combine 3 paths + transpose to (B,L,C) ----------------
__global__ __launch_bounds__(256) void k_comb(const float* __restrict__ ys, const int* __restrict__ inv,
                                              float* __restrict__ out){
    int tile = blockIdx.x & 63; int b = blockIdx.x >> 6;
    int l0 = tile * 64;
    __shared__ float t0[CC * 65];
    __shared__ int invs[64];
    if (threadIdx.x < 64) invs[threadIdx.x] = inv[b*LL + l0 + threadIdx.x];
    __syncthreads();
    const float* y0p = ys + (size_t)(b*KK + 0) * CC * LL;
    const float* y1p = ys + (size_t)(b*KK + 1) * CC * LL;
    const float* y2p = ys + (size_t)(b*KK + 2) * CC * LL;
    for (int it = 0; it < 24; it++){
        int e = it * 256 + threadIdx.x;
        int li = e & 63; int c = e >> 6;
        int l = l0 + li;
        float v = y0p[(size_t)c*LL + l] + y1p[(size_t)c*LL + (LL-1-l)] + y2p[(size_t)c*LL + invs[li]];
        t0[c*65 + li] = v * (1.0f/3.0f);
    }
    __syncthreads();
    for (int it = 0; it < 24; it++){
        int e = it * 256 + threadIdx.x;
        int c = e % CC; int li = e / CC;
        out[((size_t)b*LL + l0 + li) * CC + c] = t0[c*65 + li];
    }
}

extern "C" void kernel_launch(void* const* d_in, const int* in_sizes, int n_in,
                              void* d_out, int out_size, void* d_ws, size_t ws_size,
                              hipStream_t stream){
    const float* x    = (const float*)d_in[0];
    const float* xpw  = (const float*)d_in[1];
    const float* dtw  = (const float*)d_in[2];
    const float* dtb  = (const float*)d_in[3];
    const float* Alog = (const float*)d_in[4];
    const float* Ds   = (const float*)d_in[5];
    const float* c1w  = (const float*)d_in[6];
    const float* c1b  = (const float*)d_in[7];
    const float* ca1w = (const float*)d_in[8];
    const float* ca1b = (const float*)d_in[9];
    const float* ca2w = (const float*)d_in[10];
    const float* ca2b = (const float*)d_in[11];
    const float* lng  = (const float*)d_in[12];
    const float* lnb  = (const float*)d_in[13];
    const float* c2w  = (const float*)d_in[14];
    const float* rpet = (const float*)d_in[15];
    float* out = (float*)d_out;

    float* ws   = (float*)d_ws;
    float* xc   = ws;                      // 384
    float* ca   = xc + 384;                // 384
    float* x1   = ca + 384;                // B*C*L = 1572864
    float* rpe  = x1 + (size_t)BB*CC*LL;   // C*L = 393216
    float* posy = rpe + (size_t)CC*LL;     // B*L
    float* posx = posy + (size_t)BB*LL;
    float* path = posx + (size_t)BB*LL;
    float* xd   = path + (size_t)BB*LL;    // B*C*L
    int*   idx  = (int*)(xd + (size_t)BB*CC*LL);   // B*L ints
    int*   inv  = idx + (size_t)BB*LL;             // B*L ints
    float* u2   = (float*)(inv + (size_t)BB*LL);   // B*C*L
    float* dtA  = u2 + (size_t)BB*CC*LL;           // B*K*C*L = 4718592
    float* Bst  = dtA + (size_t)BB*KK*CC*LL;       // B*K*L*N = 786432
    float* Cst  = Bst + (size_t)BB*KK*LL*NN;
    float* ysA  = Cst + (size_t)BB*KK*LL*NN;       // B*K*C*L

    k_mean  <<<BB*CC, 256, 0, stream>>>(x, xc);
    k_ca    <<<BB, 128, 0, stream>>>(xc, ca1w, ca1b, ca2w, ca2b, ca);
    k_conv  <<<(BB*CC*LL)/256, 256, 0, stream>>>(x, c1w, c1b, ca, x1);
    k_rpe   <<<(CC*LL)/256, 256, 0, stream>>>(rpet, rpe);
    k_off   <<<(BB*LL)/256, 256, 0, stream>>>(x1, lng, lnb, c2w, posy, posx, path);
    k_sort  <<<BB, 1024, 0, stream>>>(path, idx, inv);
    k_sample<<<(BB*CC*LL)/256, 256, 0, stream>>>(x, rpe, posy, posx, xd);
    k_proj  <<<BB*KK*64, 64, 0, stream>>>(x, xd, idx, xpw, dtw, dtb, u2, dtA, Bst, Cst);
    k_scan<0><<<BB*CC, 512, 0, stream>>>(x,  dtA, Bst, Cst, Alog, Ds, ysA);
    k_scan<1><<<BB*CC, 512, 0, stream>>>(x,  dtA, Bst, Cst, Alog, Ds, ysA);
    k_scan<2><<<BB*CC, 512, 0, stream>>>(u2, dtA, Bst, Cst, Alog, Ds, ysA);
    k_comb  <<<BB*64, 256, 0, stream>>>(ysA, inv, out);
}

// Round 6
// 481.541 us; speedup vs baseline: 1.2168x; 1.0491x over previous
//
#include <hip/hip_runtime.h>

#define BB 4
#define CC 96
#define HH 64
#define WW 64
#define LL 4096
#define KK 3
#define RR 6
#define NN 16

__device__ __forceinline__ float geluf(float x){
    return 0.5f * x * (1.0f + erff(x * 0.70710678118654752f));
}
__device__ __forceinline__ float softplusf(float x){
    return fmaxf(x, 0.0f) + log1pf(expf(-fabsf(x)));
}
__device__ __forceinline__ float sigmoidf(float x){
    return 1.0f / (1.0f + expf(-x));
}

// ---------------- Kernel A: per-(b,c) spatial mean ----------------
__global__ __launch_bounds__(256) void k_mean(const float* __restrict__ x, float* __restrict__ xc){
    int bc = blockIdx.x; // 0..B*C-1
    const float* p = x + (size_t)bc * LL;
    float s = 0.f;
    for (int i = threadIdx.x; i < LL; i += 256) s += p[i];
    __shared__ float red[256];
    red[threadIdx.x] = s; __syncthreads();
    for (int st = 128; st > 0; st >>= 1){
        if (threadIdx.x < st) red[threadIdx.x] += red[threadIdx.x + st];
        __syncthreads();
    }
    if (threadIdx.x == 0) xc[bc] = red[0] * (1.0f / LL);
}

// ---------------- Kernel B: channel-attention MLP ----------------
__global__ __launch_bounds__(128) void k_ca(const float* __restrict__ xc,
                     const float* __restrict__ w1, const float* __restrict__ b1,
                     const float* __restrict__ w2, const float* __restrict__ b2,
                     float* __restrict__ ca){
    int b = blockIdx.x;
    int t = threadIdx.x;
    __shared__ float hid[CC/16];
    if (t < CC/16){
        float a = b1[t];
        for (int d = 0; d < CC; d++) a += w1[t*CC + d] * xc[b*CC + d];
        hid[t] = geluf(a);
    }
    __syncthreads();
    if (t < CC){
        float a = b2[t];
        #pragma unroll
        for (int i = 0; i < CC/16; i++) a += w2[t*(CC/16) + i] * hid[i];
        ca[b*CC + t] = sigmoidf(a);
    }
}

// ---------------- Kernel C: depthwise 9x9 conv + bias, scaled by ca ----------------
__global__ __launch_bounds__(256) void k_conv(const float* __restrict__ x, const float* __restrict__ w,
                       const float* __restrict__ bias, const float* __restrict__ ca,
                       float* __restrict__ x1){
    int gid = blockIdx.x * 256 + threadIdx.x; // B*C*L
    int l = gid & (LL-1); int bc = gid >> 12;
    int c = bc % CC; int b = bc / CC;
    int h = l >> 6, wq = l & 63;
    const float* xp = x + (size_t)bc * LL;
    const float* wp = w + c * 81;
    float acc = 0.f;
    #pragma unroll
    for (int ky = 0; ky < 9; ky++){
        int yy = h + ky - 4;
        if (yy < 0 || yy >= HH) continue;
        #pragma unroll
        for (int kx = 0; kx < 9; kx++){
            int xx = wq + kx - 4;
            if (xx < 0 || xx >= WW) continue;
            acc += xp[yy*WW + xx] * wp[ky*9 + kx];
        }
    }
    x1[gid] = (acc + bias[c]) * ca[b*CC + c];
}

// ---------------- Kernel D: rpe resize 7x7 -> 64x64 (b-independent) ----------------
__global__ __launch_bounds__(256) void k_rpe(const float* __restrict__ t, float* __restrict__ out){
    int gid = blockIdx.x * 256 + threadIdx.x; // C*L
    int l = gid & (LL-1); int c = gid >> 12;
    int h = l >> 6, w = l & 63;
    float sy = fmaxf((h + 0.5f) * (7.0f/64.0f) - 0.5f, 0.f);
    float sx = fmaxf((w + 0.5f) * (7.0f/64.0f) - 0.5f, 0.f);
    int y0 = (int)floorf(sy); int x0 = (int)floorf(sx);
    float wy = sy - (float)y0, wx = sx - (float)x0;
    int y1 = min(y0 + 1, 6), x1i = min(x0 + 1, 6);
    const float* tp = t + c * 49;
    float r0 = tp[y0*7 + x0] * (1.f - wy) + tp[y1*7 + x0] * wy;
    float r1 = tp[y0*7 + x1i] * (1.f - wy) + tp[y1*7 + x1i] * wy;
    out[gid] = r0 * (1.f - wx) + r1 * wx;
}

// ---------------- Kernel E: LayerNorm(C) + GELU + 1x1 conv -> pos/path ----------------
__global__ __launch_bounds__(256) void k_off(const float* __restrict__ x1,
                      const float* __restrict__ g, const float* __restrict__ bta,
                      const float* __restrict__ w2,
                      float* __restrict__ posy, float* __restrict__ posx, float* __restrict__ path){
    int gid = blockIdx.x * 256 + threadIdx.x; // B*L
    int l = gid & (LL-1); int b = gid >> 12;
    const float* p = x1 + (size_t)b * CC * LL + l;
    float s = 0.f, ss = 0.f;
    for (int c = 0; c < CC; c++){
        float v = p[(size_t)c * LL];
        s += v; ss += v * v;
    }
    float m = s * (1.0f / CC);
    float var = ss * (1.0f / CC) - m * m;
    float rstd = rsqrtf(var + 1e-5f);
    float a0 = 0.f, a1 = 0.f, a2 = 0.f;
    for (int c = 0; c < CC; c++){
        float v = p[(size_t)c * LL];
        float xn = (v - m) * rstd * g[c] + bta[c];
        float xg = geluf(xn);
        a0 += w2[c] * xg;
        a1 += w2[CC + c] * xg;
        a2 += w2[2*CC + c] * xg;
    }
    int h = l >> 6, w = l & 63;
    float ry = (2*h + 1) * (1.0f/63.0f) - 1.0f;
    float rx = (2*w + 1) * (1.0f/63.0f) - 1.0f;
    posy[gid] = tanhf(a0) * (1.0f/63.0f) + ry;
    posx[gid] = tanhf(a1) * (1.0f/63.0f) + rx;
    path[gid] = tanhf(a2) + ((l + 0.5f) * (2.0f/4095.0f) - 1.0f);
}

// ---------------- Kernel F: hybrid register/shuffle/LDS stable bitonic argsort ----------------
typedef unsigned long long u64s;
__device__ __forceinline__ u64s shflx64(u64s x, int m){
    int lo = __shfl_xor((int)(unsigned)x, m);
    int hi = __shfl_xor((int)(unsigned)(x >> 32), m);
    return ((u64s)(unsigned)hi << 32) | (unsigned)lo;
}
__device__ __forceinline__ void cex(u64s& a, u64s& b, bool up){
    u64s mn = a < b ? a : b;
    u64s mx = a < b ? b : a;
    a = up ? mn : mx;
    b = up ? mx : mn;
}
__global__ __launch_bounds__(1024) void k_sort(const float* __restrict__ path,
                                               int* __restrict__ idx, int* __restrict__ inv){
    int b = blockIdx.x;
    int t = threadIdx.x;
    __shared__ u64s lds[LL];
    u64s v[4];
    #pragma unroll
    for (int r = 0; r < 4; r++){
        int e = t*4 + r;
        unsigned u = __float_as_uint(path[b*LL + e]);
        u ^= (u >> 31) ? 0xFFFFFFFFu : 0x80000000u;   // monotonic float->uint
        v[r] = ((u64s)u << 32) | (unsigned)e;
    }
    for (int kk = 2; kk <= LL; kk <<= 1){
        for (int j = kk >> 1; j > 0; j >>= 1){
            if (j >= 256){
                __syncthreads();
                #pragma unroll
                for (int r = 0; r < 4; r++) lds[t*4 + r] = v[r];
                __syncthreads();
                #pragma unroll
                for (int r = 0; r < 4; r++){
                    int e = t*4 + r;
                    u64s pv = lds[e ^ j];
                    bool up    = ((e & kk) == 0);
                    bool lower = ((e & j) == 0);
                    u64s mn = v[r] < pv ? v[r] : pv;
                    u64s mx = v[r] < pv ? pv : v[r];
                    v[r] = (up == lower) ? mn : mx;
                }
            } else if (j >= 4){
                int m = j >> 2;
                #pragma unroll
                for (int r = 0; r < 4; r++){
                    u64s pv = shflx64(v[r], m);
                    bool up    = (((t*4 + r) & kk) == 0);
                    bool lower = ((t & m) == 0);
                    u64s mn = v[r] < pv ? v[r] : pv;
                    u64s mx = v[r] < pv ? pv : v[r];
                    v[r] = (up == lower) ? mn : mx;
                }
            } else if (j == 2){
                bool up = (((t*4) & kk) == 0);
                cex(v[0], v[2], up);
                cex(v[1], v[3], up);
            } else { // j == 1
                if (kk == 2){
                    cex(v[0], v[1], true);
                    cex(v[2], v[3], false);
                } else {
                    bool up = (((t*4) & kk) == 0);
                    cex(v[0], v[1], up);
                    cex(v[2], v[3], up);
                }
            }
        }
    }
    #pragma unroll
    for (int r = 0; r < 4; r++){
        int e = t*4 + r;
        int id = (int)(unsigned)(v[r] & 0xFFFFFFFFu);
        idx[b*LL + e] = id;
        inv[b*LL + id] = e;
    }
}

// ---------------- bilinear sample, zero padding ----------------
__device__ __forceinline__ float bilin0(const float* __restrict__ img, float gx, float gy){
    float fx = (gx + 1.f) * 31.5f;   // (W-1)/2 = 31.5
    float fy = (gy + 1.f) * 31.5f;
    float x0f = floorf(fx), y0f = floorf(fy);
    float wx = fx - x0f, wy = fy - y0f;
    int x0 = (int)x0f, y0 = (int)y0f;
    float acc = 0.f;
    bool vx0 = (x0 >= 0) & (x0 < WW), vx1 = (x0+1 >= 0) & (x0+1 < WW);
    bool vy0 = (y0 >= 0) & (y0 < HH), vy1 = (y0+1 >= 0) & (y0+1 < HH);
    if (vy0 & vx0) acc += img[y0*WW + x0]       * (1.f-wx) * (1.f-wy);
    if (vy0 & vx1) acc += img[y0*WW + x0+1]     * wx       * (1.f-wy);
    if (vy1 & vx0) acc += img[(y0+1)*WW + x0]   * (1.f-wx) * wy;
    if (vy1 & vx1) acc += img[(y0+1)*WW + x0+1] * wx       * wy;
    return acc;
}

// ---------------- Kernel S: x grid-sample + rpe grid-sample -> xd ----------------
__global__ __launch_bounds__(256) void k_sample(const float* __restrict__ x, const float* __restrict__ rpe,
                         const float* __restrict__ posy, const float* __restrict__ posx,
                         float* __restrict__ xd){
    int gid = blockIdx.x * 256 + threadIdx.x; // B*C*L
    int l = gid & (LL-1); int bc = gid >> 12;
    int b = bc / CC; int c = bc % CC;
    float gy = posy[b*LL + l], gx = posx[b*LL + l];
    float v = bilin0(x + (size_t)bc * LL, gx, gy);
    int h = l >> 6, w = l & 63;
    float ky = h * (128.0f/3969.0f) - 1.0f;  // linspace(0,64,64)/63*2-1
    float kx = w * (128.0f/3969.0f) - 1.0f;
    float v2 = bilin0(rpe + (size_t)c * LL, (kx - gx) * 0.5f, (ky - gy) * 0.5f);
    xd[gid] = v + v2;
}

// ---------------- Kernel G: projection, register-prefetch-96 for latency hiding ----------------
// Grid-limited occupancy (768 waves) -> VGPRs are free. Load all 96 channel
// values as one batch of independent loads (all outstanding), then 96x38 FMA
// block with SGPR weights, then stores. __launch_bounds__(64,1) frees the
// register allocator (needs ~160 VGPRs: 96 v + 38 acc).
__global__ __launch_bounds__(64, 1) void k_proj(const float* __restrict__ x, const float* __restrict__ xd,
    const int* __restrict__ indices, const float* __restrict__ xpw, const float* __restrict__ dtw,
    const float* __restrict__ dtb, float* __restrict__ u2, float* __restrict__ dt,
    float* __restrict__ Bst, float* __restrict__ Cst){
    int blk = blockIdx.x;          // B*K*64 blocks
    int ltile = blk & 63; int bk = blk >> 6;
    int k = bk % KK; int b = bk / KK;
    const float* __restrict__ Wk = xpw + k*38*CC;   // uniform per block
    int l = ltile * 64 + threadIdx.x;
    int srcl = (k == 0) ? l : (k == 1 ? (LL-1-l) : indices[b*LL + l]);
    const float* xp = (k == 2 ? xd : x) + (size_t)b * CC * LL + srcl;

    // batch-load all 96 values: independent, all in flight
    float v[CC];
    #pragma unroll
    for (int d = 0; d < CC; d++) v[d] = xp[(size_t)d * LL];

    float acc[38];
    #pragma unroll
    for (int i = 0; i < 38; i++) acc[i] = 0.f;
    #pragma unroll
    for (int d = 0; d < CC; d++){
        #pragma unroll
        for (int i = 0; i < 38; i++) acc[i] += Wk[i*CC + d] * v[d];
    }

    size_t base = ((size_t)bk * LL + l) * NN;
    #pragma unroll
    for (int n = 0; n < NN; n++){
        Bst[base + n] = acc[RR + n];
        Cst[base + n] = acc[RR + NN + n];
    }
    if (k == 2){
        float* up = u2 + (size_t)b * CC * LL + l;
        #pragma unroll
        for (int d = 0; d < CC; d++) up[(size_t)d * LL] = v[d];
    }
    const float* __restrict__ Dw = dtw + k*CC*RR;
    const float* __restrict__ Db = dtb + k*CC;
    float* dtp = dt + (size_t)bk * CC * LL + l;
    #pragma unroll 8
    for (int d = 0; d < CC; d++){
        float sdt = Db[d];
        #pragma unroll
        for (int r = 0; r < RR; r++) sdt += acc[r] * Dw[d*RR + r];
        dtp[(size_t)d * LL] = softplusf(sdt);
    }
}

// ---------------- Kernel H: chunked-parallel selective scan (templated source/direction) ----------------
// KIND 0: u = x forward; KIND 1: u = x reversed; KIND 2: u = u2 forward.
#define ST 32          // segments
#define TT 128         // steps per segment
template<int KIND>
__global__ __launch_bounds__(512) void k_scan(const float* __restrict__ usrc,
    const float* __restrict__ dt, const float* __restrict__ Bst, const float* __restrict__ Cst,
    const float* __restrict__ Alog, const float* __restrict__ Ds, float* __restrict__ ys){
    constexpr int k = KIND;
    int blk = blockIdx.x;              // b*CC + d
    int d = blk % CC; int b = blk / CC;
    int bk = b * KK + k;
    int tid = threadIdx.x;
    int n = tid & 15; int s = tid >> 4;      // s in [0,32)
    int t0 = s * TT;

    float A  = -__expf(Alog[(k*CC + d)*NN + n]);
    float Dv = Ds[k*CC + d];

    const float* dtp = dt + ((size_t)bk * CC + d) * LL + t0;
    const float* up = (KIND == 1)
        ? usrc + ((size_t)b*CC + d) * LL + (LL-1-t0)
        : usrc + ((size_t)b*CC + d) * LL + t0;
    const float* Bp = Bst + ((size_t)bk * LL + t0) * NN + n;
    const float* Cp = Cst + ((size_t)bk * LL + t0) * NN + n;
    float* yp = ys + ((size_t)bk * CC + d) * LL + t0;

    // Phase 1: local segment scan from h=0, track product of a
    float Aprod = 1.f, h = 0.f;
    #pragma unroll 8
    for (int t = 0; t < TT; t++){
        float dtv = dtp[t];
        float uv  = (KIND == 1) ? up[-t] : up[t];
        float Bv  = Bp[t * NN];
        float a = __expf(dtv * A);
        Aprod *= a;
        h = fmaf(a, h, dtv * uv * Bv);
    }

    // Phase 2: exclusive scan of (Aprod, h) over segments, per chain n
    __shared__ float sA[ST*16];
    __shared__ float sB[ST*16];
    __shared__ float sCin[ST*16];
    sA[s*16 + n] = Aprod;
    sB[s*16 + n] = h;
    __syncthreads();
    if (tid < 16){
        float c = 0.f;
        #pragma unroll
        for (int ss = 0; ss < ST; ss++){
            sCin[ss*16 + tid] = c;
            c = fmaf(sA[ss*16 + tid], c, sB[ss*16 + tid]);
        }
    }
    __syncthreads();
    float hc = sCin[s*16 + n];

    // Phase 3: replay with carry-in, emit y
    #pragma unroll 4
    for (int t = 0; t < TT; t++){
        float dtv = dtp[t];
        float uv  = (KIND == 1) ? up[-t] : up[t];
        float Bv  = Bp[t * NN];
        float Cv  = Cp[t * NN];
        float a = __expf(dtv * A);
        hc = fmaf(a, hc, dtv * uv * Bv);
        float p = hc * Cv;
        p += __shfl_xor(p, 1);
        p += __shfl_xor(p, 2);
        p += __shfl_xor(p, 4);
        p += __shfl_xor(p, 8);
        if (n == 0) yp[t] = fmaf(uv, Dv, p);
    }
}

// ---------------- Kernel I: combine 3 paths + transpose to (B,L,C) ----------------
__global__ __launch_bounds__(256) void k_comb(const float* __restrict__ ys, const int* __restrict__ inv,
                                              float* __restrict__ out){
    int tile = blockIdx.x & 63; int b = blockIdx.x >> 6;
    int l0 = tile * 64;
    __shared__ float t0[CC * 65];
    __shared__ int invs[64];
    if (threadIdx.x < 64) invs[threadIdx.x] = inv[b*LL + l0 + threadIdx.x];
    __syncthreads();
    const float* y0p = ys + (size_t)(b*KK + 0) * CC * LL;
    const float* y1p = ys + (size_t)(b*KK + 1) * CC * LL;
    const float* y2p = ys + (size_t)(b*KK + 2) * CC * LL;
    for (int it = 0; it < 24; it++){
        int e = it * 256 + threadIdx.x;
        int li = e & 63; int c = e >> 6;
        int l = l0 + li;
        float v = y0p[(size_t)c*LL + l] + y1p[(size_t)c*LL + (LL-1-l)] + y2p[(size_t)c*LL + invs[li]];
        t0[c*65 + li] = v * (1.0f/3.0f);
    }
    __syncthreads();
    for (int it = 0; it < 24; it++){
        int e = it * 256 + threadIdx.x;
        int c = e % CC; int li = e / CC;
        out[((size_t)b*LL + l0 + li) * CC + c] = t0[c*65 + li];
    }
}

extern "C" void kernel_launch(void* const* d_in, const int* in_sizes, int n_in,
                              void* d_out, int out_size, void* d_ws, size_t ws_size,
                              hipStream_t stream){
    const float* x    = (const float*)d_in[0];
    const float* xpw  = (const float*)d_in[1];
    const float* dtw  = (const float*)d_in[2];
    const float* dtb  = (const float*)d_in[3];
    const float* Alog = (const float*)d_in[4];
    const float* Ds   = (const float*)d_in[5];
    const float* c1w  = (const float*)d_in[6];
    const float* c1b  = (const float*)d_in[7];
    const float* ca1w = (const float*)d_in[8];
    const float* ca1b = (const float*)d_in[9];
    const float* ca2w = (const float*)d_in[10];
    const float* ca2b = (const float*)d_in[11];
    const float* lng  = (const float*)d_in[12];
    const float* lnb  = (const float*)d_in[13];
    const float* c2w  = (const float*)d_in[14];
    const float* rpet = (const float*)d_in[15];
    float* out = (float*)d_out;

    float* ws   = (float*)d_ws;
    float* xc   = ws;                      // 384
    float* ca   = xc + 384;                // 384
    float* x1   = ca + 384;                // B*C*L = 1572864
    float* rpe  = x1 + (size_t)BB*CC*LL;   // C*L = 393216
    float* posy = rpe + (size_t)CC*LL;     // B*L
    float* posx = posy + (size_t)BB*LL;
    float* path = posx + (size_t)BB*LL;
    float* xd   = path + (size_t)BB*LL;    // B*C*L
    int*   idx  = (int*)(xd + (size_t)BB*CC*LL);   // B*L ints
    int*   inv  = idx + (size_t)BB*LL;             // B*L ints
    float* u2   = (float*)(inv + (size_t)BB*LL);   // B*C*L
    float* dtA  = u2 + (size_t)BB*CC*LL;           // B*K*C*L = 4718592
    float* Bst  = dtA + (size_t)BB*KK*CC*LL;       // B*K*L*N = 786432
    float* Cst  = Bst + (size_t)BB*KK*LL*NN;
    float* ysA  = Cst + (size_t)BB*KK*LL*NN;       // B*K*C*L

    k_mean  <<<BB*CC, 256, 0, stream>>>(x, xc);
    k_ca    <<<BB, 128, 0, stream>>>(xc, ca1w, ca1b, ca2w, ca2b, ca);
    k_conv  <<<(BB*CC*LL)/256, 256, 0, stream>>>(x, c1w, c1b, ca, x1);
    k_rpe   <<<(CC*LL)/256, 256, 0, stream>>>(rpet, rpe);
    k_off   <<<(BB*LL)/256, 256, 0, stream>>>(x1, lng, lnb, c2w, posy, posx, path);
    k_sort  <<<BB, 1024, 0, stream>>>(path, idx, inv);
    k_sample<<<(BB*CC*LL)/256, 256, 0, stream>>>(x, rpe, posy, posx, xd);
    k_proj  <<<BB*KK*64, 64, 0, stream>>>(x, xd, idx, xpw, dtw, dtb, u2, dtA, Bst, Cst);
    k_scan<0><<<BB*CC, 512, 0, stream>>>(x,  dtA, Bst, Cst, Alog, Ds, ysA);
    k_scan<1><<<BB*CC, 512, 0, stream>>>(x,  dtA, Bst, Cst, Alog, Ds, ysA);
    k_scan<2><<<BB*CC, 512, 0, stream>>>(u2, dtA, Bst, Cst, Alog, Ds, ysA);
    k_comb  <<<BB*64, 256, 0, stream>>>(ysA, inv, out);
}